// Round 7
// baseline (439.295 us; speedup 1.0000x reference)
//
#include <hip/hip_runtime.h>
#include <cfloat>

#define N_TOK   32768
#define DIM     64
#define K_CODES 8192
#define KP      8                    // K partitions (argmin split, merged with tie-break)
#define KPC     (K_CODES / KP)       // 1024 codes per partition
#define CB      64                   // codes per LDS chunk
#define NCH     (KPC / CB)           // 16 chunks per partition
#define TB      128                  // tokens per block
#define TBLK    (N_TOK / TB)         // 256 token blocks
#define LSZ     132                  // zT row stride (2-way banks, 16B aligned)
#define LSE     68                   // eT row stride (2-way banks, 16B aligned)

#define IDX_OFF  (N_TOK * DIM)
#define LOSS_OFF (N_TOK * DIM + N_TOK)

// workspace layout (float units)
#define WS_ESQ    0
#define WS_BEST   (WS_ESQ + K_CODES)          // KP * N_TOK floats
#define WS_PIDX   (WS_BEST + KP * N_TOK)      // KP * N_TOK ints
#define WS_PART   (WS_PIDX + KP * N_TOK)      // 128 floats

// ---------------------------------------------------------------------------
// e_sq[k] = numpy-pairwise sum of squares of embedding row k (bitwise np order)
// ---------------------------------------------------------------------------
__global__ __launch_bounds__(256) void esq_kernel(const float* __restrict__ emb,
                                                  float* __restrict__ esq) {
#pragma clang fp contract(off)
    const int tid = threadIdx.x;
    const int q = tid & 7;
    const int code = blockIdx.x * 32 + (tid >> 3);
    const float* row = emb + code * DIM;
    float x = row[q];
    float r = x * x;
#pragma unroll
    for (int m = 1; m < 8; ++m) {
        float y = row[q + 8 * m];
        float sq = y * y;
        r = r + sq;
    }
    r = r + __shfl_xor(r, 1, 64);
    r = r + __shfl_xor(r, 2, 64);
    r = r + __shfl_xor(r, 4, 64);
    if (q == 0) esq[code] = r;
}

// ---------------------------------------------------------------------------
// Distance scan (R6 structure, LDS shrunk for 3 blocks/CU):
// block = 128 tokens x 1024-code partition (16 chunks of 64 codes).
// 16tx x 16ty threads, thread tile = 8 tokens x 4 codes (acc = 32 VGPR).
// Thread's codes (ascending): {4tx .. 4tx+3} within each chunk.
// LDS 51.7 KB -> 3 blocks/CU -> staging/barriers overlap another block's FMAs.
// ---------------------------------------------------------------------------
__global__ __launch_bounds__(256, 3) void vq_scan(const float* __restrict__ hid,
                                                  const float* __restrict__ emb,
                                                  const float* __restrict__ esq,
                                                  float* __restrict__ pbest,
                                                  int* __restrict__ pidx) {
#pragma clang fp contract(off)
    __shared__ float zT[DIM][LSZ];    // zT[j][t], t in [0,128)
    __shared__ float eT[DIM][LSE];    // eT[j][c], c in [0,64)
    __shared__ float zsq_s[TB];

    const int tid = threadIdx.x;
    const int bid = blockIdx.x;
    const int kp  = bid >> 8;                 // partition 0..7
    const int tb  = (bid & (TBLK - 1)) * TB;  // token base
    const int k0  = kp * KPC;

    // ---- stage z tile, transposed (32 floats per thread) ----
    {
        const int tr = tid >> 1;            // token row 0..127
        const int tj0 = (tid & 1) * 32;     // j-range start
        const float4* h4 = reinterpret_cast<const float4*>(hid + (size_t)(tb + tr) * DIM + tj0);
        float4 v[8];
#pragma unroll
        for (int i = 0; i < 8; ++i) v[i] = h4[i];
#pragma unroll
        for (int i = 0; i < 8; ++i) {
            const int j = tj0 + 4 * i;
            zT[j + 0][tr] = v[i].x;
            zT[j + 1][tr] = v[i].y;
            zT[j + 2][tr] = v[i].z;
            zT[j + 3][tr] = v[i].w;
        }
    }
    __syncthreads();

    // ---- z_sq per token, numpy pairwise order (threads 0..127) ----
    if (tid < TB) {
        const int t = tid;
        float r[8];
#pragma unroll
        for (int q = 0; q < 8; ++q) {
            float x = zT[q][t];
            r[q] = x * x;
#pragma unroll
            for (int m = 1; m < 8; ++m) {
                float y = zT[q + 8 * m][t];
                float sq = y * y;
                r[q] = r[q] + sq;
            }
        }
        const float s01 = r[0] + r[1], s23 = r[2] + r[3];
        const float s45 = r[4] + r[5], s67 = r[6] + r[7];
        zsq_s[t] = (s01 + s23) + (s45 + s67);
    }

    const int tx = tid & 15;        // code lane
    const int ty = tid >> 4;        // token group
    const int tg = ty * 8;          // 8 tokens per thread
    const int cg = tx * 4;          // code quad within chunk

    // prefetch chunk 0 into registers (global->reg->LDS pipeline)
    const int pc  = tid >> 2;            // code row 0..63 within chunk
    const int pj0 = (tid & 3) * 16;      // j quarter
    float4 pref[4];
    {
        const float4* e4 = reinterpret_cast<const float4*>(
            emb + (size_t)(k0 + pc) * DIM + pj0);
#pragma unroll
        for (int i = 0; i < 4; ++i) pref[i] = e4[i];
    }
    __syncthreads();                // zsq_s ready

    float zsq_r[8];
#pragma unroll
    for (int a = 0; a < 8; ++a) zsq_r[a] = zsq_s[tg + a];

    float best[8];
    int   bidx[8];
#pragma unroll
    for (int a = 0; a < 8; ++a) { best[a] = FLT_MAX; bidx[a] = 0; }

    for (int ch = 0; ch < NCH; ++ch) {
        // write prefetched chunk to LDS (transposed)
#pragma unroll
        for (int i = 0; i < 4; ++i) {
            const int j = pj0 + 4 * i;
            eT[j + 0][pc] = pref[i].x;
            eT[j + 1][pc] = pref[i].y;
            eT[j + 2][pc] = pref[i].z;
            eT[j + 3][pc] = pref[i].w;
        }
        __syncthreads();

        // prefetch next chunk (hides under compute below)
        if (ch + 1 < NCH) {
            const float4* e4 = reinterpret_cast<const float4*>(
                emb + (size_t)(k0 + (ch + 1) * CB + pc) * DIM + pj0);
#pragma unroll
            for (int i = 0; i < 4; ++i) pref[i] = e4[i];
        }

        const int kb = k0 + ch * CB;
        const float4 es0 = *reinterpret_cast<const float4*>(esq + kb + cg);

        float acc[8][4];
#pragma unroll
        for (int a = 0; a < 8; ++a)
#pragma unroll
            for (int b = 0; b < 4; ++b) acc[a][b] = 0.f;

        // sequential-j FMA chains: bitwise-matches BLAS k-sequential accumulation
#pragma unroll 8
        for (int j = 0; j < DIM; ++j) {
            const float4 zv0 = *reinterpret_cast<const float4*>(&zT[j][tg]);
            const float4 zv1 = *reinterpret_cast<const float4*>(&zT[j][tg + 4]);
            const float4 ev0 = *reinterpret_cast<const float4*>(&eT[j][cg]);
            const float za[8] = {zv0.x, zv0.y, zv0.z, zv0.w, zv1.x, zv1.y, zv1.z, zv1.w};
            const float eb[4] = {ev0.x, ev0.y, ev0.z, ev0.w};
#pragma unroll
            for (int a = 0; a < 8; ++a)
#pragma unroll
                for (int b = 0; b < 4; ++b)
                    acc[a][b] = fmaf(za[a], eb[b], acc[a][b]);
        }

        // d = fl( fl(z_sq + e_sq) - 2*dot ); strict < keeps earliest index
        const float esv[4] = {es0.x, es0.y, es0.z, es0.w};
#pragma unroll
        for (int b = 0; b < 4; ++b) {
            const int k = kb + cg + b;
#pragma unroll
            for (int a = 0; a < 8; ++a) {
                const float s = zsq_r[a] + esv[b];
                const float d = fmaf(-2.0f, acc[a][b], s);
                if (d < best[a]) { best[a] = d; bidx[a] = k; }
            }
        }
        __syncthreads();
    }

    // ---- combine across the 16 lanes sharing a token group (first-index ties) ----
#pragma unroll
    for (int off = 1; off < 16; off <<= 1) {
#pragma unroll
        for (int a = 0; a < 8; ++a) {
            const float ov = __shfl_xor(best[a], off, 64);
            const int   oi = __shfl_xor(bidx[a], off, 64);
            if (ov < best[a] || (ov == best[a] && oi < bidx[a])) {
                best[a] = ov; bidx[a] = oi;
            }
        }
    }

    if (tx == 0) {
#pragma unroll
        for (int a = 0; a < 8; ++a) {
            const int t = tb + tg + a;
            pbest[kp * N_TOK + t] = best[a];
            pidx [kp * N_TOK + t] = bidx[a];
        }
    }
}

// ---------------------------------------------------------------------------
// Merge partitions (ascending p + strict < == np first-occurrence), outputs.
// ---------------------------------------------------------------------------
__global__ __launch_bounds__(256) void vq_finish(const float* __restrict__ hid,
                                                 const float* __restrict__ emb,
                                                 const float* __restrict__ pbest,
                                                 const int* __restrict__ pidx,
                                                 float* __restrict__ out_zq,
                                                 float* __restrict__ out_idx,
                                                 float* __restrict__ partials) {
#pragma clang fp contract(off)
    __shared__ float lred[4];
    const int tid = threadIdx.x;
    const int t = blockIdx.x * 256 + tid;

    float best = pbest[t];
    int   bi   = pidx[t];
#pragma unroll
    for (int p = 1; p < KP; ++p) {
        const float b = pbest[p * N_TOK + t];
        const int   i = pidx [p * N_TOK + t];
        if (b < best) { best = b; bi = i; }
    }
    out_idx[t] = (float)bi;

    const float4* q4 = reinterpret_cast<const float4*>(emb + (size_t)bi * DIM);
    const float4* h4 = reinterpret_cast<const float4*>(hid + (size_t)t * DIM);
    float4* o4 = reinterpret_cast<float4*>(out_zq + (size_t)t * DIM);
    float lsum = 0.f;
#pragma unroll
    for (int i = 0; i < 16; ++i) {
        const float4 q = q4[i];
        const float4 h = h4[i];
        float4 zq;
        float dx;
        dx = q.x - h.x; zq.x = h.x + dx; lsum += dx * dx;
        dx = q.y - h.y; zq.y = h.y + dx; lsum += dx * dx;
        dx = q.z - h.z; zq.z = h.z + dx; lsum += dx * dx;
        dx = q.w - h.w; zq.w = h.w + dx; lsum += dx * dx;
        o4[i] = zq;
    }

#pragma unroll
    for (int off = 32; off >= 1; off >>= 1) lsum += __shfl_xor(lsum, off, 64);
    const int wid = tid >> 6;
    if ((tid & 63) == 0) lred[wid] = lsum;
    __syncthreads();
    if (tid == 0) partials[blockIdx.x] = (lred[0] + lred[1]) + (lred[2] + lred[3]);
}

// ---------------------------------------------------------------------------
// Final loss over 128 block partials
// ---------------------------------------------------------------------------
__global__ __launch_bounds__(128) void loss_kernel(const float* __restrict__ partials,
                                                   float* __restrict__ out_loss) {
#pragma clang fp contract(off)
    __shared__ float s[128];
    const int t = threadIdx.x;
    s[t] = partials[t];
    __syncthreads();
    for (int off = 64; off >= 1; off >>= 1) {
        if (t < off) s[t] = s[t] + s[t + off];
        __syncthreads();
    }
    if (t == 0) {
        const float m = s[0] * (1.0f / 2097152.0f);  // exact: /2^21
        out_loss[0] = m + 0.25f * m;
    }
}

extern "C" void kernel_launch(void* const* d_in, const int* in_sizes, int n_in,
                              void* d_out, int out_size, void* d_ws, size_t ws_size,
                              hipStream_t stream) {
    const float* hid = (const float*)d_in[0];
    const float* emb = (const float*)d_in[1];
    float* out = (float*)d_out;
    float* ws  = (float*)d_ws;
    float* esq   = ws + WS_ESQ;
    float* pbest = ws + WS_BEST;
    int*   pidx  = (int*)(ws + WS_PIDX);
    float* parts = ws + WS_PART;

    esq_kernel<<<K_CODES / 32, 256, 0, stream>>>(emb, esq);
    vq_scan<<<TBLK * KP, 256, 0, stream>>>(hid, emb, esq, pbest, pidx);
    vq_finish<<<N_TOK / 256, 256, 0, stream>>>(hid, emb, pbest, pidx,
                                               out, out + IDX_OFF, parts);
    loss_kernel<<<1, 128, 0, stream>>>(parts, out + LOSS_OFF);
}